// Round 10
// baseline (383.984 us; speedup 1.0000x reference)
//
#include <hip/hip_runtime.h>
#include <math.h>

// Problem constants (from reference)
#define B 4
#define H 2
#define L 2048
#define DM 32          // d_model
#define F 16           // feat dim
#define HD 16          // head dim
#define DD 273         // 1 + F + F*F taylor feature dim
#define DDP 280        // padded feature rows
#define CHK 64         // chunk length
#define NC (L / CHK)   // 32 chunks
#define BH (B * H)     // 8
#define HCHK 32        // half-chunk (p-split)

#define SC_LIN 0.5f                   // 1/RRD, RRD=2
#define SC_QUAD 0.17677669529663687f  // 1/(RD*sqrt(2)) = 1/(4*sqrt(2))

#define PREP 8  // probe amplification

// ===========================================================================
// REAL PIPELINE (identical to round 9; passes with absmax 1.95e-3)
// ===========================================================================

__global__ __launch_bounds__(256) void chunksum_kernel(
    const float* __restrict__ hs, const float* __restrict__ Wq,
    const float* __restrict__ Wk, const float* __restrict__ Wv,
    float* __restrict__ qp, float* __restrict__ kp, float* __restrict__ vp,
    float* __restrict__ S_kv, float* __restrict__ S_k) {
  int blk = blockIdx.x;  // (bh*NC + ch)*2 + half
  int half = blk & 1;
  int bc = blk >> 1;
  int bh = bc >> 5, ch = bc & (NC - 1);
  int b = bh >> 1, h = bh & 1;

  __shared__ float ks[HCHK][F + 1];

  int r = threadIdx.x & 31;
  int g = threadIdx.x >> 5;
  int l = ch * CHK + half * HCHK + r;
  float x[DM];
  const float4* xr = (const float4*)(hs + ((size_t)b * L + l) * DM);
#pragma unroll
  for (int j = 0; j < DM / 4; j++) {
    float4 v = xr[j];
    x[4 * j] = v.x; x[4 * j + 1] = v.y; x[4 * j + 2] = v.z; x[4 * j + 3] = v.w;
  }
#pragma unroll
  for (int q = 0; q < 6; q++) {
    int c = g * 6 + q;
    int kind = c >> 4;
    int f = c & 15;
    const float* __restrict__ W = (kind == 0) ? Wq : (kind == 1) ? Wk : Wv;
    const float* wr = W + (size_t)(h * 16 + f) * DM;
    float acc = 0.f;
#pragma unroll
    for (int i = 0; i < DM; i++) acc += x[i] * wr[i];
    float* dst = (kind == 0) ? qp : (kind == 1) ? kp : vp;
    dst[((size_t)bh * L + l) * F + f] = acc;
    if (kind == 1) ks[r][f] = acc;
  }
  if (threadIdx.x < HCHK) ks[threadIdx.x][16] = 1.0f;
  __syncthreads();

  const float* __restrict__ vbase =
      vp + ((size_t)bh * L + (size_t)ch * CHK + half * HCHK) * F;
  size_t sblk = (size_t)half * (BH * NC) + bc;

#pragma unroll
  for (int rep = 0; rep < 2; rep++) {
    int dd = threadIdx.x + rep * 256;
    if (dd >= DDP) break;
    float* dst = S_kv + (sblk * DDP + dd) * HD;
    if (dd >= DD) {
#pragma unroll
      for (int hh = 0; hh < HD; hh++) dst[hh] = 0.f;
      S_k[sblk * DDP + dd] = 0.f;
      continue;
    }
    int i, j;
    float sc;
    if (dd == 0) {
      i = 16; j = 16; sc = 1.0f;
    } else if (dd <= F) {
      i = dd - 1; j = 16; sc = SC_LIN;
    } else {
      int m = dd - 17;
      i = m >> 4; j = m & 15; sc = SC_QUAD;
    }
    float acc[HD];
#pragma unroll
    for (int hh = 0; hh < HD; hh++) acc[hh] = 0.f;
    float acck = 0.f;
    for (int p = 0; p < HCHK; p++) {
      float kf = sc * ks[p][i] * ks[p][j];
      acck += kf;
      const float4* vr = (const float4*)(vbase + p * F);
      float4 v0 = vr[0], v1 = vr[1], v2 = vr[2], v3 = vr[3];
      acc[0] += kf * v0.x;  acc[1] += kf * v0.y;
      acc[2] += kf * v0.z;  acc[3] += kf * v0.w;
      acc[4] += kf * v1.x;  acc[5] += kf * v1.y;
      acc[6] += kf * v1.z;  acc[7] += kf * v1.w;
      acc[8] += kf * v2.x;  acc[9] += kf * v2.y;
      acc[10] += kf * v2.z; acc[11] += kf * v2.w;
      acc[12] += kf * v3.x; acc[13] += kf * v3.y;
      acc[14] += kf * v3.z; acc[15] += kf * v3.w;
    }
#pragma unroll
    for (int hh = 0; hh < HD; hh++) dst[hh] = acc[hh];
    S_k[sblk * DDP + dd] = acck;
  }
}

#define PSLICES 19
__global__ __launch_bounds__(256) void prefix_kernel(
    const float* __restrict__ S_kv, const float* __restrict__ S_k,
    float* __restrict__ P_kv, float* __restrict__ P_k) {
  int blk = blockIdx.x;
  int bh = blk / PSLICES, sl = blk % PSLICES;
  int e = sl * 256 + threadIdx.x;
  const size_t HS_KV = (size_t)BH * NC * DDP * HD;
  const size_t HS_K = (size_t)BH * NC * DDP;
  if (e < DDP * HD) {
    size_t base = (size_t)bh * NC * DDP * HD + e;
    float run = 0.f;
#pragma unroll
    for (int c = 0; c < NC; c++) {
      size_t idx = base + (size_t)c * DDP * HD;
      float v = S_kv[idx] + S_kv[idx + HS_KV];
      P_kv[idx] = run;
      run += v;
    }
  } else if (e < DDP * HD + DDP) {
    int e2 = e - DDP * HD;
    size_t base = (size_t)bh * NC * DDP + e2;
    float run = 0.f;
#pragma unroll
    for (int c = 0; c < NC; c++) {
      size_t idx = base + (size_t)c * DDP;
      float v = S_k[idx] + S_k[idx + HS_K];
      P_k[idx] = run;
      run += v;
    }
  }
}

__global__ __launch_bounds__(512) void outchunk_kernel(
    const float* __restrict__ qp, const float* __restrict__ kp,
    const float* __restrict__ vp, const float* __restrict__ St_kv,
    const float* __restrict__ St_k, float* __restrict__ y) {
  int blk = blockIdx.x;
  int bh = blk >> 5, ch = blk & (NC - 1);
  int b = bh >> 1, h = bh & 1;
  int t = threadIdx.x & 63;
  int u = __builtin_amdgcn_readfirstlane(threadIdx.x >> 6);

  __shared__ float qs[CHK][F + 1];
  __shared__ float red[8][CHK][21];

  if (threadIdx.x < 256) {
    const float4* qb =
        (const float4*)(qp + ((size_t)bh * L + (size_t)ch * CHK) * F);
    int r = threadIdx.x >> 2, c4 = (threadIdx.x & 3) * 4;
    float4 v = qb[threadIdx.x];
    qs[r][c4] = v.x; qs[r][c4 + 1] = v.y;
    qs[r][c4 + 2] = v.z; qs[r][c4 + 3] = v.w;
    if (threadIdx.x < CHK) qs[threadIdx.x][16] = 1.0f;
  }

  float qreg[F];
  const float4* qrow =
      (const float4*)(qp + ((size_t)bh * L + (size_t)ch * CHK + t) * F);
#pragma unroll
  for (int j = 0; j < 4; j++) {
    float4 v = qrow[j];
    qreg[4 * j] = v.x; qreg[4 * j + 1] = v.y;
    qreg[4 * j + 2] = v.z; qreg[4 * j + 3] = v.w;
  }
  __syncthreads();

  float acc[HD];
#pragma unroll
  for (int hh = 0; hh < HD; hh++) acc[hh] = 0.f;
  float den = 0.f;

  const float* __restrict__ Sbase = St_kv + (size_t)blk * DDP * HD;
  const float* __restrict__ Skb = St_k + (size_t)blk * DDP;

#pragma unroll 5
  for (int m = 0; m < 35; m++) {
    int dd = u + (m << 3);
    float phi;
    if (dd == 0) {
      phi = 1.0f;
    } else if (dd <= F) {
      phi = qs[t][dd - 1] * SC_LIN;
    } else {
      int mm = dd - 17;
      phi = qs[t][mm >> 4] * qs[t][mm & 15] * SC_QUAD;
    }
    phi = (dd < DD) ? phi : 0.0f;
    den += phi * Skb[dd];
    const float4* Sr = (const float4*)(Sbase + dd * HD);
    float4 s0 = Sr[0], s1 = Sr[1], s2 = Sr[2], s3 = Sr[3];
    acc[0] += phi * s0.x;  acc[1] += phi * s0.y;
    acc[2] += phi * s0.z;  acc[3] += phi * s0.w;
    acc[4] += phi * s1.x;  acc[5] += phi * s1.y;
    acc[6] += phi * s1.z;  acc[7] += phi * s1.w;
    acc[8] += phi * s2.x;  acc[9] += phi * s2.y;
    acc[10] += phi * s2.z; acc[11] += phi * s2.w;
    acc[12] += phi * s3.x; acc[13] += phi * s3.y;
    acc[14] += phi * s3.z; acc[15] += phi * s3.w;
  }

  const float* __restrict__ kbase = kp + ((size_t)bh * L + (size_t)ch * CHK) * F;
  const float* __restrict__ vbase = vp + ((size_t)bh * L + (size_t)ch * CHK) * F;
#pragma unroll
  for (int mm = 0; mm < CHK / 8; mm++) {
    int s = u + mm * 8;
    const float4* kr = (const float4*)(kbase + s * F);
    float4 k0 = kr[0], k1 = kr[1], k2 = kr[2], k3 = kr[3];
    float dot = qreg[0] * k0.x + qreg[1] * k0.y + qreg[2] * k0.z +
                qreg[3] * k0.w + qreg[4] * k1.x + qreg[5] * k1.y +
                qreg[6] * k1.z + qreg[7] * k1.w + qreg[8] * k2.x +
                qreg[9] * k2.y + qreg[10] * k2.z + qreg[11] * k2.w +
                qreg[12] * k3.x + qreg[13] * k3.y + qreg[14] * k3.z +
                qreg[15] * k3.w;
    float scv = 1.0f + dot * 0.25f + dot * dot * 0.03125f;
    scv = (s <= t) ? scv : 0.0f;
    den += scv;
    const float4* vr = (const float4*)(vbase + s * F);
    float4 v0 = vr[0], v1 = vr[1], v2 = vr[2], v3 = vr[3];
    acc[0] += scv * v0.x;  acc[1] += scv * v0.y;
    acc[2] += scv * v0.z;  acc[3] += scv * v0.w;
    acc[4] += scv * v1.x;  acc[5] += scv * v1.y;
    acc[6] += scv * v1.z;  acc[7] += scv * v1.w;
    acc[8] += scv * v2.x;  acc[9] += scv * v2.y;
    acc[10] += scv * v2.z; acc[11] += scv * v2.w;
    acc[12] += scv * v3.x; acc[13] += scv * v3.y;
    acc[14] += scv * v3.z; acc[15] += scv * v3.w;
  }

#pragma unroll
  for (int hh = 0; hh < HD; hh++) red[u][t][hh] = acc[hh];
  red[u][t][16] = den;
  __syncthreads();

  for (int idx = threadIdx.x; idx < CHK * 17; idx += 512) {
    int t2 = idx / 17, e = idx % 17;
    float sum = 0.f;
#pragma unroll
    for (int w = 0; w < 8; w++) sum += red[w][t2][e];
    red[0][t2][e] = sum;
  }
  __syncthreads();

  if (threadIdx.x < CHK) {
    int t2 = threadIdx.x;
    float inv = 1.0f / (red[0][t2][16] + 1e-12f);
    float* yb = y + (((size_t)(b * L + ch * CHK + t2)) * H + h) * HD;
#pragma unroll
    for (int hh = 0; hh < HD; hh++) yb[hh] = red[0][t2][hh] * inv;
  }
}

__global__ __launch_bounds__(256) void out_kernel(const float* __restrict__ y,
                                                  const float* __restrict__ Wo,
                                                  float* __restrict__ out) {
  int lane = threadIdx.x & 63;
  int wave = __builtin_amdgcn_readfirstlane(threadIdx.x >> 6);
  int row = blockIdx.x * 64 + lane;
  float yr[DM];
  const float4* yb = (const float4*)(y + (size_t)row * DM);
#pragma unroll
  for (int j = 0; j < DM / 4; j++) {
    float4 v = yb[j];
    yr[4 * j] = v.x; yr[4 * j + 1] = v.y; yr[4 * j + 2] = v.z; yr[4 * j + 3] = v.w;
  }
  for (int c = wave * 8; c < wave * 8 + 8; c++) {
    const float* __restrict__ wr = Wo + (size_t)c * DM;
    float acc = 0.f;
#pragma unroll
    for (int i = 0; i < DM; i++) acc += yr[i] * wr[i];
    out[(size_t)row * DM + c] = acc;
  }
}

// ===========================================================================
// PROBES (x8 amplified, write to dead scratch; isolate chunksum's phases)
// ===========================================================================

// P1: phase-1 only (R6-style projection: 12 channels/thread, 64 rows/block).
__global__ __launch_bounds__(256) void probe_proj(
    const float* __restrict__ hs, const float* __restrict__ Wq,
    const float* __restrict__ Wk, const float* __restrict__ Wv,
    float* __restrict__ qp2, float* __restrict__ kp2, float* __restrict__ vp2) {
  int blk = blockIdx.x;  // bh*NC + ch
  int bh = blk >> 5, ch = blk & (NC - 1);
  int b = bh >> 1, h = bh & 1;
  int lane = threadIdx.x & 63, wave = threadIdx.x >> 6;
  int l = ch * CHK + lane;
  for (int rep = 0; rep < PREP; rep++) {
    asm volatile("" ::: "memory");
    float x[DM];
    const float4* xr = (const float4*)(hs + ((size_t)b * L + l) * DM);
#pragma unroll
    for (int j = 0; j < DM / 4; j++) {
      float4 v = xr[j];
      x[4 * j] = v.x; x[4 * j + 1] = v.y;
      x[4 * j + 2] = v.z; x[4 * j + 3] = v.w;
    }
    for (int c = wave * 12; c < wave * 12 + 12; c++) {
      int kind = c >> 4;
      int f = c & 15;
      const float* __restrict__ W = (kind == 0) ? Wq : (kind == 1) ? Wk : Wv;
      const float* wr = W + (size_t)(h * 16 + f) * DM;
      float acc = 0.f;
#pragma unroll
      for (int i = 0; i < DM; i++) acc += x[i] * wr[i];
      float* dst = (kind == 0) ? qp2 : (kind == 1) ? kp2 : vp2;
      dst[((size_t)bh * L + l) * F + f] = acc;
    }
  }
}

// P2: phase-2 only, R6 structure (full 64-p loop, v fp32 in LDS, no unroll).
__global__ __launch_bounds__(256) void probe_p2(
    const float* __restrict__ kp, const float* __restrict__ vp,
    float* __restrict__ S2kv, float* __restrict__ S2k) {
  int blk = blockIdx.x;  // bh*NC + ch
  int bh = blk >> 5, ch = blk & (NC - 1);
  __shared__ float ks[CHK][F + 1];
  __shared__ float vs[CHK][F];
  {
    const float4* kb = (const float4*)(kp + ((size_t)bh * L + (size_t)ch * CHK) * F);
    const float4* vb = (const float4*)(vp + ((size_t)bh * L + (size_t)ch * CHK) * F);
    int r = threadIdx.x >> 2, c4 = (threadIdx.x & 3) * 4;
    float4 v = kb[threadIdx.x];
    ks[r][c4] = v.x; ks[r][c4 + 1] = v.y; ks[r][c4 + 2] = v.z; ks[r][c4 + 3] = v.w;
    ((float4*)vs)[threadIdx.x] = vb[threadIdx.x];
    if (threadIdx.x < CHK) ks[threadIdx.x][16] = 1.0f;
  }
  __syncthreads();

  for (int rep = 0; rep < PREP; rep++) {
    asm volatile("" ::: "memory");
#pragma unroll
    for (int rep2 = 0; rep2 < 2; rep2++) {
      int dd = threadIdx.x + rep2 * 256;
      if (dd >= DDP) break;
      float* dst = S2kv + ((size_t)blk * DDP + dd) * HD;
      if (dd >= DD) {
#pragma unroll
        for (int hh = 0; hh < HD; hh++) dst[hh] = 0.f;
        S2k[(size_t)blk * DDP + dd] = 0.f;
        continue;
      }
      int i, j;
      float sc;
      if (dd == 0) {
        i = 16; j = 16; sc = 1.0f;
      } else if (dd <= F) {
        i = dd - 1; j = 16; sc = SC_LIN;
      } else {
        int m = dd - 17;
        i = m >> 4; j = m & 15; sc = SC_QUAD;
      }
      float acc[HD];
#pragma unroll
      for (int hh = 0; hh < HD; hh++) acc[hh] = 0.f;
      float acck = 0.f;
      for (int p = 0; p < CHK; p++) {  // no unroll (R6 behavior)
        float kf = sc * ks[p][i] * ks[p][j];
        acck += kf;
        const float4* vr = (const float4*)vs[p];
        float4 v0 = vr[0], v1 = vr[1], v2 = vr[2], v3 = vr[3];
        acc[0] += kf * v0.x;  acc[1] += kf * v0.y;
        acc[2] += kf * v0.z;  acc[3] += kf * v0.w;
        acc[4] += kf * v1.x;  acc[5] += kf * v1.y;
        acc[6] += kf * v1.z;  acc[7] += kf * v1.w;
        acc[8] += kf * v2.x;  acc[9] += kf * v2.y;
        acc[10] += kf * v2.z; acc[11] += kf * v2.w;
        acc[12] += kf * v3.x; acc[13] += kf * v3.y;
        acc[14] += kf * v3.z; acc[15] += kf * v3.w;
      }
#pragma unroll
      for (int hh = 0; hh < HD; hh++) dst[hh] = acc[hh];
      S2k[(size_t)blk * DDP + dd] = acck;
    }
  }
}

// P3: phase-2 candidate (half-split grid 512 = 2 blocks/CU, 32-p loop
// unrolled x4, v fp32 in LDS).
__global__ __launch_bounds__(256) void probe_p3(
    const float* __restrict__ kp, const float* __restrict__ vp,
    float* __restrict__ S3kv, float* __restrict__ S3k) {
  int blk = blockIdx.x;  // (bh*NC+ch)*2 + half
  int half = blk & 1;
  int bc = blk >> 1;
  int bh = bc >> 5, ch = bc & (NC - 1);
  __shared__ float ks[HCHK][F + 1];
  __shared__ float vs[HCHK][F];
  {
    size_t rowbase = ((size_t)bh * L + (size_t)ch * CHK + half * HCHK) * F;
    if (threadIdx.x < 128) {
      const float4* kb = (const float4*)(kp + rowbase);
      int r = threadIdx.x >> 2, c4 = (threadIdx.x & 3) * 4;
      float4 v = kb[threadIdx.x];
      ks[r][c4] = v.x; ks[r][c4 + 1] = v.y;
      ks[r][c4 + 2] = v.z; ks[r][c4 + 3] = v.w;
    } else {
      const float4* vb = (const float4*)(vp + rowbase);
      ((float4*)vs)[threadIdx.x - 128] = vb[threadIdx.x - 128];
    }
    if (threadIdx.x < HCHK) ks[threadIdx.x][16] = 1.0f;
  }
  __syncthreads();

  size_t sblk = (size_t)half * (BH * NC) + bc;
  for (int rep = 0; rep < PREP; rep++) {
    asm volatile("" ::: "memory");
#pragma unroll
    for (int rep2 = 0; rep2 < 2; rep2++) {
      int dd = threadIdx.x + rep2 * 256;
      if (dd >= DDP) break;
      float* dst = S3kv + (sblk * DDP + dd) * HD;
      if (dd >= DD) {
#pragma unroll
        for (int hh = 0; hh < HD; hh++) dst[hh] = 0.f;
        S3k[sblk * DDP + dd] = 0.f;
        continue;
      }
      int i, j;
      float sc;
      if (dd == 0) {
        i = 16; j = 16; sc = 1.0f;
      } else if (dd <= F) {
        i = dd - 1; j = 16; sc = SC_LIN;
      } else {
        int m = dd - 17;
        i = m >> 4; j = m & 15; sc = SC_QUAD;
      }
      float acc[HD];
#pragma unroll
      for (int hh = 0; hh < HD; hh++) acc[hh] = 0.f;
      float acck = 0.f;
#pragma unroll 4
      for (int p = 0; p < HCHK; p++) {
        float kf = sc * ks[p][i] * ks[p][j];
        acck += kf;
        const float4* vr = (const float4*)vs[p];
        float4 v0 = vr[0], v1 = vr[1], v2 = vr[2], v3 = vr[3];
        acc[0] += kf * v0.x;  acc[1] += kf * v0.y;
        acc[2] += kf * v0.z;  acc[3] += kf * v0.w;
        acc[4] += kf * v1.x;  acc[5] += kf * v1.y;
        acc[6] += kf * v1.z;  acc[7] += kf * v1.w;
        acc[8] += kf * v2.x;  acc[9] += kf * v2.y;
        acc[10] += kf * v2.z; acc[11] += kf * v2.w;
        acc[12] += kf * v3.x; acc[13] += kf * v3.y;
        acc[14] += kf * v3.z; acc[15] += kf * v3.w;
      }
#pragma unroll
      for (int hh = 0; hh < HD; hh++) dst[hh] = acc[hh];
      S3k[sblk * DDP + dd] = acck;
    }
  }
}

extern "C" void kernel_launch(void* const* d_in, const int* in_sizes, int n_in,
                              void* d_out, int out_size, void* d_ws,
                              size_t ws_size, hipStream_t stream) {
  const float* hs = (const float*)d_in[0];
  const float* Wq = (const float*)d_in[1];
  const float* Wk = (const float*)d_in[2];
  const float* Wv = (const float*)d_in[3];
  const float* Wo = (const float*)d_in[4];
  float* out = (float*)d_out;

  float* ws = (float*)d_ws;
  float* qp = ws;                                      // BH*L*F = 262144
  float* kp = qp + (size_t)BH * L * F;                 // 262144
  float* vp = kp + (size_t)BH * L * F;                 // 262144
  float* S_kv = vp + (size_t)BH * L * F;               // 2*BH*NC*DDP*HD
  float* S_k = S_kv + (size_t)2 * BH * NC * DDP * HD;  // 2*BH*NC*DDP
  float* P_kv = S_k + (size_t)2 * BH * NC * DDP;       // BH*NC*DDP*HD
  float* P_k = P_kv + (size_t)BH * NC * DDP * HD;      // BH*NC*DDP
  float* y = P_k + (size_t)BH * NC * DDP;              // B*L*H*HD
  // probe scratch (dead stores)
  float* qp2 = y + (size_t)B * L * H * HD;
  float* kp2 = qp2 + (size_t)BH * L * F;
  float* vp2 = kp2 + (size_t)BH * L * F;
  float* S2kv = vp2 + (size_t)BH * L * F;
  float* S2k = S2kv + (size_t)BH * NC * DDP * HD;
  float* S3kv = S2k + (size_t)BH * NC * DDP;
  float* S3k = S3kv + (size_t)2 * BH * NC * DDP * HD;
  // total ~35 MB fp32 workspace

  // real pipeline (round-9 structure, correct output)
  chunksum_kernel<<<BH * NC * 2, 256, 0, stream>>>(hs, Wq, Wk, Wv, qp, kp, vp,
                                                   S_kv, S_k);
  prefix_kernel<<<BH * PSLICES, 256, 0, stream>>>(S_kv, S_k, P_kv, P_k);
  outchunk_kernel<<<BH * NC, 512, 0, stream>>>(qp, kp, vp, P_kv, P_k, y);
  out_kernel<<<B * L / 64, 256, 0, stream>>>(y, Wo, out);

  // diagnostic probes (amplified x8; outputs dead)
  probe_proj<<<BH * NC, 256, 0, stream>>>(hs, Wq, Wk, Wv, qp2, kp2, vp2);
  probe_p2<<<BH * NC, 256, 0, stream>>>(kp, vp, S2kv, S2k);
  probe_p3<<<BH * NC * 2, 256, 0, stream>>>(kp, vp, S3kv, S3k);
}